// Round 9
// baseline (3529.934 us; speedup 1.0000x reference)
//
#include <hip/hip_runtime.h>
#include <math.h>

#define B_ROWS 16384
#define K_CB   512
#define D_DIM  256
#define NSEG   511
#define NG     4            // 4 column groups of 128 cols each

// ws float layout:
//   sls  @ 0      (512)
//   cs   @ 512    (512)
//   cc   @ 1024   (512)
//   wbnd @ 1536   (3 * 16384)   boundary cols 128,256,384 dotted with all z rows
//   zz   @ 50688  (16384)       per-row ||z||^2
//   cand @ 67072  (float4 x 16384 x 4)
#define WS_WBND 1536
#define WS_ZZ   50688
#define WS_CAND 67072

// ---------- kernel 0: segment constants + boundary dots + zz ----------
__global__ __launch_bounds__(256) void prologue_kernel(const float* __restrict__ z,
                                                       const float* __restrict__ cb,
                                                       float* __restrict__ sls,
                                                       float* __restrict__ cs,
                                                       float* __restrict__ cc,
                                                       float* __restrict__ wbnd,
                                                       float* __restrict__ zz) {
    int bid = blockIdx.x;
    int t = threadIdx.x;
    int lane = t & 63;
    if (bid < 128) {
        // segment constants: 4 segments per block, one wave each
        int j = bid * 4 + (t >> 6);
        if (j == NSEG) {            // pad slot 511 with benign values
            if (lane == 0) { sls[NSEG] = 1e30f; cs[NSEG] = 0.f; cc[NSEG] = 0.f; }
            return;
        }
        float4 a = reinterpret_cast<const float4*>(cb + (size_t)j * D_DIM)[lane];
        float4 b = reinterpret_cast<const float4*>(cb + (size_t)(j + 1) * D_DIM)[lane];
        float sx = b.x - a.x, sy = b.y - a.y, sz = b.z - a.z, sw = b.w - a.w;
        float p0 = sx*sx + sy*sy + sz*sz + sw*sw;
        float p1 = a.x*sx + a.y*sy + a.z*sz + a.w*sw;
        float p2 = a.x*a.x + a.y*a.y + a.z*a.z + a.w*a.w;
        #pragma unroll
        for (int m = 32; m >= 1; m >>= 1) {
            p0 += __shfl_xor(p0, m);
            p1 += __shfl_xor(p1, m);
            p2 += __shfl_xor(p2, m);
        }
        if (lane == 0) { sls[j] = p0 + 1e-8f; cs[j] = p1; cc[j] = p2; }
    } else {
        // boundary dots + zz: 4 rows per block, one wave each
        int row = (bid - 128) * 4 + (t >> 6);
        float4 zv = reinterpret_cast<const float4*>(z + (size_t)row * D_DIM)[lane];
        float pz = zv.x*zv.x + zv.y*zv.y + zv.z*zv.z + zv.w*zv.w;
        #pragma unroll
        for (int m = 32; m >= 1; m >>= 1) pz += __shfl_xor(pz, m);
        if (lane == 0) zz[row] = pz;
        #pragma unroll
        for (int gi = 0; gi < 3; ++gi) {
            int col = 128 * (gi + 1);
            float4 cv = reinterpret_cast<const float4*>(cb + (size_t)col * D_DIM)[lane];
            float p = zv.x*cv.x + zv.y*cv.y + zv.z*cv.z + zv.w*cv.w;
            #pragma unroll
            for (int m = 32; m >= 1; m >>= 1) p += __shfl_xor(p, m);
            if (lane == 0) wbnd[(size_t)gi * B_ROWS + row] = p;
        }
    }
}

// ---------- kernel 1: 128x128 GEMM tile + in-register segment scan ----------
// Double-buffered LDS, 1-iteration register prefetch, single barrier per kc.
__global__ __launch_bounds__(256, 2) void main_kernel(const float* __restrict__ z,
                                                      const float* __restrict__ cb,
                                                      const float* __restrict__ sls_g,
                                                      const float* __restrict__ cs_g,
                                                      const float* __restrict__ cc_g,
                                                      const float* __restrict__ wbnd,
                                                      float4* __restrict__ cand) {
    __shared__ __align__(16) float zs[2][128][36];   // 36-float stride: 16B-mult rows
    __shared__ __align__(16) float csh[2][128][36];  // total 73.7 KB (+0.5K below) -> 2 blk/CU
    __shared__ float sl_s[128], cs_s[128], cc_s[128];

    int t = threadIdx.x;
    int row0 = blockIdx.x * 128;
    int g = blockIdx.y;
    int col0 = g * 128;
    int tr = t >> 4;          // 0..15 -> rows tr + 16*r
    int tc = t & 15;          // 0..15 -> cols tc + 16*c
    int l = t & 63;

    if (t < 128) {
        sl_s[t] = sls_g[col0 + t];
        cs_s[t] = cs_g[col0 + t];
        cc_s[t] = cc_g[col0 + t];
    }

    float acc[8][8];
    #pragma unroll
    for (int r = 0; r < 8; ++r)
        #pragma unroll
        for (int c = 0; c < 8; ++c) acc[r][c] = 0.f;

    // stage kc=0 into buf0 (through regs)
    float4 pz[4], pc[4];
    #pragma unroll
    for (int i = 0; i < 4; ++i) {
        int f = i * 256 + t, r = f >> 3, kq = f & 7;
        pz[i] = *reinterpret_cast<const float4*>(z + (size_t)(row0 + r) * D_DIM + kq * 4);
        pc[i] = *reinterpret_cast<const float4*>(cb + (size_t)(col0 + r) * D_DIM + kq * 4);
    }
    #pragma unroll
    for (int i = 0; i < 4; ++i) {
        int f = i * 256 + t, r = f >> 3, kq = f & 7;
        *reinterpret_cast<float4*>(&zs[0][r][kq * 4]) = pz[i];
        *reinterpret_cast<float4*>(&csh[0][r][kq * 4]) = pc[i];
    }
    __syncthreads();

    #pragma unroll
    for (int kc = 0; kc < 8; ++kc) {
        const int cur = kc & 1;
        // prefetch kc+1 into regs; latency hidden under the k4 compute below
        if (kc < 7) {
            int d0 = (kc + 1) * 32;
            #pragma unroll
            for (int i = 0; i < 4; ++i) {
                int f = i * 256 + t, r = f >> 3, kq = f & 7;
                pz[i] = *reinterpret_cast<const float4*>(z + (size_t)(row0 + r) * D_DIM + d0 + kq * 4);
                pc[i] = *reinterpret_cast<const float4*>(cb + (size_t)(col0 + r) * D_DIM + d0 + kq * 4);
            }
        }
        #pragma unroll
        for (int k4 = 0; k4 < 8; ++k4) {
            float4 za[8];
            #pragma unroll
            for (int r = 0; r < 8; ++r)
                za[r] = *reinterpret_cast<const float4*>(&zs[cur][tr + 16 * r][k4 * 4]);
            #pragma unroll
            for (int c = 0; c < 8; ++c) {
                float4 cv = *reinterpret_cast<const float4*>(&csh[cur][tc + 16 * c][k4 * 4]);
                #pragma unroll
                for (int r = 0; r < 8; ++r) {
                    acc[r][c] += za[r].x * cv.x;
                    acc[r][c] += za[r].y * cv.y;
                    acc[r][c] += za[r].z * cv.z;
                    acc[r][c] += za[r].w * cv.w;
                }
            }
        }
        if (kc < 7) {
            // all waves passed the last barrier => done reading buf cur^1; safe to overwrite
            #pragma unroll
            for (int i = 0; i < 4; ++i) {
                int f = i * 256 + t, r = f >> 3, kq = f & 7;
                *reinterpret_cast<float4*>(&zs[cur ^ 1][r][kq * 4]) = pz[i];
                *reinterpret_cast<float4*>(&csh[cur ^ 1][r][kq * 4]) = pc[i];
            }
            __syncthreads();
        }
    }

    // boundary column w (col0+128) for the last segment of groups 0..2
    float wbv[8];
    #pragma unroll
    for (int r = 0; r < 8; ++r) wbv[r] = 0.f;
    if (g < 3 && tc == 15) {
        #pragma unroll
        for (int r = 0; r < 8; ++r)
            wbv[r] = wbnd[(size_t)g * B_ROWS + row0 + tr + 16 * r];
    }

    // in-register scan: segment j = col0 + tc + 16*c needs w_j (own) and w_{j+1}.
    // w_{j+1} for tc<15  : lane l+1, same chunk c           (shA)
    // w_{j+1} for tc==15 : lane tc=0 (l&48), chunk c+1      (firstw[c+1])
    //                      or wbnd for the last chunk (c==7)
    #pragma unroll
    for (int r = 0; r < 8; ++r) {
        int row = tr + 16 * r;
        float firstw[8];
        #pragma unroll
        for (int c = 1; c < 8; ++c) firstw[c] = __shfl(acc[r][c], l & 48);
        float bd = 1e38f; int bj = 0x3fffffff; float bt = 0.f;
        #pragma unroll
        for (int c = 0; c < 8; ++c) {
            float w0 = acc[r][c];
            float shA = __shfl(w0, l + 1);                 // lane tc+1's w (same c)
            float w1 = (tc == 15) ? ((c < 7) ? firstw[c + 1] : wbv[r]) : shA;
            int jl = tc + 16 * c;
            int j = col0 + jl;
            float slsj = sl_s[jl], csj = cs_s[jl], ccj = cc_s[jl];
            float dot = w1 - w0 - csj;
            float tt = fminf(fmaxf(dot / slsj, 0.f), 1.f);
            // relative distance (true d2 minus row-constant zz): rank-preserving
            float d2 = ccj - 2.f * w0 + tt * (tt * slsj - 2.f * dot);
            if (j < NSEG && d2 < bd) { bd = d2; bj = j; bt = tt; }
        }
        // argmin across the 16-lane column group (first index on ties)
        #pragma unroll
        for (int m = 1; m <= 8; m <<= 1) {
            float od = __shfl_xor(bd, m);
            int   oj = __shfl_xor(bj, m);
            float ot = __shfl_xor(bt, m);
            if (od < bd || (od == bd && oj < bj)) { bd = od; bj = oj; bt = ot; }
        }
        if (tc == 0)
            cand[(size_t)(row0 + row) * NG + g] = make_float4(bd, bt, (float)bj, 0.f);
    }
}

// ---------- kernel 2: combine groups + write outputs (8 rows/block, 2048 blocks) ----------
__global__ __launch_bounds__(256) void combine_kernel(const float4* __restrict__ cand,
                                                      const float* __restrict__ cb,
                                                      const float* __restrict__ zz,
                                                      float* __restrict__ out) {
    float* out_bp  = out;
    float* out_idx = out + (size_t)B_ROWS * D_DIM;
    float* out_t   = out_idx + B_ROWS;
    float* out_d   = out_t + B_ROWS;

    __shared__ float sj[8];
    __shared__ float st8[8];

    int t = threadIdx.x;
    int row0 = blockIdx.x * 8;
    if (t < 8) {
        int row = row0 + t;
        const float4* cp = cand + (size_t)row * NG;
        float4 c0 = cp[0], c1 = cp[1], c2 = cp[2], c3 = cp[3];
        float bd = c0.x, bt = c0.y, bj = c0.z;
        if (c1.x < bd) { bd = c1.x; bt = c1.y; bj = c1.z; }   // groups ascending in j:
        if (c2.x < bd) { bd = c2.x; bt = c2.y; bj = c2.z; }   // strict < == first-index ties
        if (c3.x < bd) { bd = c3.x; bt = c3.y; bj = c3.z; }
        sj[t] = bj; st8[t] = bt;
        out_idx[row] = bj;
        out_t[row]   = bt;
        out_d[row]   = sqrtf(fmaxf(bd + zz[row], 0.f));
    }
    __syncthreads();

    int lane = t & 63, w = t >> 6;     // 4 waves x 2 iterations = 8 rows
    #pragma unroll
    for (int it = 0; it < 2; ++it) {
        int rl = it * 4 + w;
        int j = (int)sj[rl];
        float tt = st8[rl];
        float4 a = reinterpret_cast<const float4*>(cb + (size_t)j * D_DIM)[lane];
        float4 b = reinterpret_cast<const float4*>(cb + (size_t)(j + 1) * D_DIM)[lane];
        float4 bp = make_float4(a.x + tt * (b.x - a.x),
                                a.y + tt * (b.y - a.y),
                                a.z + tt * (b.z - a.z),
                                a.w + tt * (b.w - a.w));
        reinterpret_cast<float4*>(out_bp + (size_t)(row0 + rl) * D_DIM)[lane] = bp;
    }
}

extern "C" void kernel_launch(void* const* d_in, const int* in_sizes, int n_in,
                              void* d_out, int out_size, void* d_ws, size_t ws_size,
                              hipStream_t stream) {
    const float* z  = (const float*)d_in[0];
    const float* cb = (const float*)d_in[1];
    float* ws  = (float*)d_ws;
    float* sls  = ws;
    float* cs   = ws + 512;
    float* cc   = ws + 1024;
    float* wbnd = ws + WS_WBND;
    float* zz   = ws + WS_ZZ;
    float4* cand = (float4*)(ws + WS_CAND);
    float* out = (float*)d_out;

    prologue_kernel<<<128 + B_ROWS / 4, 256, 0, stream>>>(z, cb, sls, cs, cc, wbnd, zz);
    main_kernel<<<dim3(B_ROWS / 128, NG), 256, 0, stream>>>(z, cb, sls, cs, cc, wbnd, cand);
    combine_kernel<<<B_ROWS / 8, 256, 0, stream>>>(cand, cb, zz, out);
}

// Round 12
// 140.507 us; speedup vs baseline: 25.1229x; 25.1229x over previous
//
#include <hip/hip_runtime.h>
#include <math.h>

#define B_ROWS 16384
#define K_CB   512
#define D_DIM  256
#define NSEG   511
#define NG     4            // 4 column groups of 128 cols each

// ws float layout:
//   sls  @ 0      (512)
//   cs   @ 512    (512)
//   cc   @ 1024   (512)
//   wbnd @ 1536   (3 * 16384)   boundary cols 128,256,384 dotted with all z rows
//   zz   @ 50688  (16384)       per-row ||z||^2
//   cand @ 67072  (float4 x 16384 x 4)
#define WS_WBND 1536
#define WS_ZZ   50688
#define WS_CAND 67072

// ---------- kernel 0: segment constants + boundary dots + zz ----------
__global__ __launch_bounds__(256) void prologue_kernel(const float* __restrict__ z,
                                                       const float* __restrict__ cb,
                                                       float* __restrict__ sls,
                                                       float* __restrict__ cs,
                                                       float* __restrict__ cc,
                                                       float* __restrict__ wbnd,
                                                       float* __restrict__ zz) {
    int bid = blockIdx.x;
    int t = threadIdx.x;
    int lane = t & 63;
    if (bid < 128) {
        // segment constants: 4 segments per block, one wave each
        int j = bid * 4 + (t >> 6);
        if (j == NSEG) {            // pad slot 511 with benign values
            if (lane == 0) { sls[NSEG] = 1e30f; cs[NSEG] = 0.f; cc[NSEG] = 0.f; }
            return;
        }
        float4 a = reinterpret_cast<const float4*>(cb + (size_t)j * D_DIM)[lane];
        float4 b = reinterpret_cast<const float4*>(cb + (size_t)(j + 1) * D_DIM)[lane];
        float sx = b.x - a.x, sy = b.y - a.y, sz = b.z - a.z, sw = b.w - a.w;
        float p0 = sx*sx + sy*sy + sz*sz + sw*sw;
        float p1 = a.x*sx + a.y*sy + a.z*sz + a.w*sw;
        float p2 = a.x*a.x + a.y*a.y + a.z*a.z + a.w*a.w;
        #pragma unroll
        for (int m = 32; m >= 1; m >>= 1) {
            p0 += __shfl_xor(p0, m);
            p1 += __shfl_xor(p1, m);
            p2 += __shfl_xor(p2, m);
        }
        if (lane == 0) { sls[j] = p0 + 1e-8f; cs[j] = p1; cc[j] = p2; }
    } else {
        // boundary dots + zz: 4 rows per block, one wave each
        int row = (bid - 128) * 4 + (t >> 6);
        float4 zv = reinterpret_cast<const float4*>(z + (size_t)row * D_DIM)[lane];
        float pz = zv.x*zv.x + zv.y*zv.y + zv.z*zv.z + zv.w*zv.w;
        #pragma unroll
        for (int m = 32; m >= 1; m >>= 1) pz += __shfl_xor(pz, m);
        if (lane == 0) zz[row] = pz;
        #pragma unroll
        for (int gi = 0; gi < 3; ++gi) {
            int col = 128 * (gi + 1);
            float4 cv = reinterpret_cast<const float4*>(cb + (size_t)col * D_DIM)[lane];
            float p = zv.x*cv.x + zv.y*cv.y + zv.z*cv.z + zv.w*cv.w;
            #pragma unroll
            for (int m = 32; m >= 1; m >>= 1) p += __shfl_xor(p, m);
            if (lane == 0) wbnd[(size_t)gi * B_ROWS + row] = p;
        }
    }
}

// ---------- kernel 1: 128x128 GEMM tile + in-register segment scan ----------
// Round-7 proven version: single-buffer LDS, 2 barriers/kc, no reg prefetch
// (reg-prefetch variant spilled to scratch at the 128-VGPR cap: 7.8 GB HBM, 3.5 ms)
__global__ __launch_bounds__(256, 2) void main_kernel(const float* __restrict__ z,
                                                      const float* __restrict__ cb,
                                                      const float* __restrict__ sls_g,
                                                      const float* __restrict__ cs_g,
                                                      const float* __restrict__ cc_g,
                                                      const float* __restrict__ wbnd,
                                                      float4* __restrict__ cand) {
    __shared__ __align__(16) float zs[128][36];   // stride 36: 144B rows (16B-mult), banks ok
    __shared__ __align__(16) float csh[128][36];
    __shared__ float sl_s[128], cs_s[128], cc_s[128];

    int t = threadIdx.x;
    int row0 = blockIdx.x * 128;
    int g = blockIdx.y;
    int col0 = g * 128;
    int tr = t >> 4;          // 0..15 -> rows tr + 16*r
    int tc = t & 15;          // 0..15 -> cols tc + 16*c
    int l = t & 63;

    if (t < 128) {
        sl_s[t] = sls_g[col0 + t];
        cs_s[t] = cs_g[col0 + t];
        cc_s[t] = cc_g[col0 + t];
    }

    float acc[8][8];
    #pragma unroll
    for (int r = 0; r < 8; ++r)
        #pragma unroll
        for (int c = 0; c < 8; ++c) acc[r][c] = 0.f;

    for (int kc = 0; kc < 8; ++kc) {
        int d0 = kc * 32;
        __syncthreads();
        // stage 128x32 z tile and 128x32 codebook tile
        #pragma unroll
        for (int i = 0; i < 4; ++i) {
            int f = i * 256 + t;          // 0..1023
            int r = f >> 3;               // 0..127
            int kq = f & 7;               // float4 slot
            float4 v = *reinterpret_cast<const float4*>(z + (size_t)(row0 + r) * D_DIM + d0 + kq * 4);
            *reinterpret_cast<float4*>(&zs[r][kq * 4]) = v;
            float4 w = *reinterpret_cast<const float4*>(cb + (size_t)(col0 + r) * D_DIM + d0 + kq * 4);
            *reinterpret_cast<float4*>(&csh[r][kq * 4]) = w;
        }
        __syncthreads();
        #pragma unroll
        for (int k4 = 0; k4 < 8; ++k4) {
            float4 za[8];
            #pragma unroll
            for (int r = 0; r < 8; ++r)
                za[r] = *reinterpret_cast<const float4*>(&zs[tr + 16 * r][k4 * 4]);
            #pragma unroll
            for (int c = 0; c < 8; ++c) {
                float4 cv = *reinterpret_cast<const float4*>(&csh[tc + 16 * c][k4 * 4]);
                #pragma unroll
                for (int r = 0; r < 8; ++r) {
                    acc[r][c] += za[r].x * cv.x;
                    acc[r][c] += za[r].y * cv.y;
                    acc[r][c] += za[r].z * cv.z;
                    acc[r][c] += za[r].w * cv.w;
                }
            }
        }
    }

    // boundary column w (col0+128) for the last segment of groups 0..2
    float wbv[8];
    #pragma unroll
    for (int r = 0; r < 8; ++r) wbv[r] = 0.f;
    if (g < 3 && tc == 15) {
        #pragma unroll
        for (int r = 0; r < 8; ++r)
            wbv[r] = wbnd[(size_t)g * B_ROWS + row0 + tr + 16 * r];
    }

    // in-register scan: segment j = col0 + tc + 16*c needs w_j (own) and w_{j+1}.
    // w_{j+1} for tc<15  : lane l+1, same chunk c           (shA)
    // w_{j+1} for tc==15 : lane tc=0 (l&48), chunk c+1      (firstw[c+1])
    //                      or wbnd for the last chunk (c==7)
    #pragma unroll
    for (int r = 0; r < 8; ++r) {
        int row = tr + 16 * r;
        // broadcast each chunk's first-column (tc=0) value to all 16 lanes
        float firstw[8];
        #pragma unroll
        for (int c = 1; c < 8; ++c) firstw[c] = __shfl(acc[r][c], l & 48);
        float bd = 1e38f; int bj = 0x3fffffff; float bt = 0.f;
        #pragma unroll
        for (int c = 0; c < 8; ++c) {
            float w0 = acc[r][c];
            float shA = __shfl(w0, l + 1);                 // lane tc+1's w (same c)
            float w1 = (tc == 15) ? ((c < 7) ? firstw[c + 1] : wbv[r]) : shA;
            int jl = tc + 16 * c;
            int j = col0 + jl;
            float slsj = sl_s[jl], csj = cs_s[jl], ccj = cc_s[jl];
            float dot = w1 - w0 - csj;
            float tt = fminf(fmaxf(dot / slsj, 0.f), 1.f);
            // relative distance (true d2 minus row-constant zz): rank-preserving
            float d2 = ccj - 2.f * w0 + tt * (tt * slsj - 2.f * dot);
            if (j < NSEG && d2 < bd) { bd = d2; bj = j; bt = tt; }
        }
        // argmin across the 16-lane column group (first index on ties)
        #pragma unroll
        for (int m = 1; m <= 8; m <<= 1) {
            float od = __shfl_xor(bd, m);
            int   oj = __shfl_xor(bj, m);
            float ot = __shfl_xor(bt, m);
            if (od < bd || (od == bd && oj < bj)) { bd = od; bj = oj; bt = ot; }
        }
        if (tc == 0)
            cand[(size_t)(row0 + row) * NG + g] = make_float4(bd, bt, (float)bj, 0.f);
    }
}

// ---------- kernel 2: combine groups + write outputs (8 rows/block, 2048 blocks) ----------
__global__ __launch_bounds__(256) void combine_kernel(const float4* __restrict__ cand,
                                                      const float* __restrict__ cb,
                                                      const float* __restrict__ zz,
                                                      float* __restrict__ out) {
    float* out_bp  = out;
    float* out_idx = out + (size_t)B_ROWS * D_DIM;
    float* out_t   = out_idx + B_ROWS;
    float* out_d   = out_t + B_ROWS;

    __shared__ float sj[8];
    __shared__ float st8[8];

    int t = threadIdx.x;
    int row0 = blockIdx.x * 8;
    if (t < 8) {
        int row = row0 + t;
        const float4* cp = cand + (size_t)row * NG;
        float4 c0 = cp[0], c1 = cp[1], c2 = cp[2], c3 = cp[3];
        float bd = c0.x, bt = c0.y, bj = c0.z;
        if (c1.x < bd) { bd = c1.x; bt = c1.y; bj = c1.z; }   // groups ascending in j:
        if (c2.x < bd) { bd = c2.x; bt = c2.y; bj = c2.z; }   // strict < == first-index ties
        if (c3.x < bd) { bd = c3.x; bt = c3.y; bj = c3.z; }
        sj[t] = bj; st8[t] = bt;
        out_idx[row] = bj;
        out_t[row]   = bt;
        out_d[row]   = sqrtf(fmaxf(bd + zz[row], 0.f));
    }
    __syncthreads();

    int lane = t & 63, w = t >> 6;     // 4 waves x 2 iterations = 8 rows
    #pragma unroll
    for (int it = 0; it < 2; ++it) {
        int rl = it * 4 + w;
        int j = (int)sj[rl];
        float tt = st8[rl];
        float4 a = reinterpret_cast<const float4*>(cb + (size_t)j * D_DIM)[lane];
        float4 b = reinterpret_cast<const float4*>(cb + (size_t)(j + 1) * D_DIM)[lane];
        float4 bp = make_float4(a.x + tt * (b.x - a.x),
                                a.y + tt * (b.y - a.y),
                                a.z + tt * (b.z - a.z),
                                a.w + tt * (b.w - a.w));
        reinterpret_cast<float4*>(out_bp + (size_t)(row0 + rl) * D_DIM)[lane] = bp;
    }
}

extern "C" void kernel_launch(void* const* d_in, const int* in_sizes, int n_in,
                              void* d_out, int out_size, void* d_ws, size_t ws_size,
                              hipStream_t stream) {
    const float* z  = (const float*)d_in[0];
    const float* cb = (const float*)d_in[1];
    float* ws  = (float*)d_ws;
    float* sls  = ws;
    float* cs   = ws + 512;
    float* cc   = ws + 1024;
    float* wbnd = ws + WS_WBND;
    float* zz   = ws + WS_ZZ;
    float4* cand = (float4*)(ws + WS_CAND);
    float* out = (float*)d_out;

    prologue_kernel<<<128 + B_ROWS / 4, 256, 0, stream>>>(z, cb, sls, cs, cc, wbnd, zz);
    main_kernel<<<dim3(B_ROWS / 128, NG), 256, 0, stream>>>(z, cb, sls, cs, cc, wbnd, cand);
    combine_kernel<<<B_ROWS / 8, 256, 0, stream>>>(cand, cb, zz, out);
}